// Round 12
// baseline (1035.239 us; speedup 1.0000x reference)
//
#include <hip/hip_runtime.h>

#define B_  2
#define S_  2048
#define D_  2048
#define H_  16
#define DH_ 128
#define L_  512
#define M_  (B_*S_)

typedef unsigned short u16;
typedef float f32x4 __attribute__((ext_vector_type(4)));
typedef short short8 __attribute__((ext_vector_type(8)));
typedef u16 u16x4 __attribute__((ext_vector_type(4)));
typedef u16 u16x8 __attribute__((ext_vector_type(8)));

__device__ inline float bf2f(u16 u) {
    union { unsigned int i; float f; } x; x.i = ((unsigned int)u) << 16; return x.f;
}
__device__ inline u16 f2bf(float f) {
    union { float f; unsigned int i; } x; x.f = f;
    unsigned int r = x.i + 0x7FFFu + ((x.i >> 16) & 1u);
    return (u16)(r >> 16);
}
__device__ inline f32x4 mfma16(short8 a, short8 b, f32x4 c) {
    return __builtin_amdgcn_mfma_f32_16x16x32_bf16(a, b, c, 0, 0, 0);
}

typedef const __attribute__((address_space(1))) unsigned int gu32;
typedef __attribute__((address_space(3))) unsigned int lu32;
__device__ inline void gload16(const u16* g, u16* l) {
    __builtin_amdgcn_global_load_lds((gu32*)g, (lu32*)l, 16, 0, 0);
}

template <typename T> __device__ inline void store1(T* p, float v);
template <> __device__ inline void store1<float>(float* p, float v) { *p = v; }
template <> __device__ inline void store1<u16>(u16* p, float v) { *p = f2bf(v); }

// ---------------------------------------------------------------------------
// MFMA GEMM: C[M][N] = A[M][K] @ B[N][K]^T, A/B bf16, f32 accum, TC out.
// 128x128 tile, 4 waves, BK=32, global_load_lds, k-slice LDS layout.
// ---------------------------------------------------------------------------
template <typename TC>
__global__ __launch_bounds__(256) void mgemm(const u16* __restrict__ A,
                                             const u16* __restrict__ Bm,
                                             TC* __restrict__ C,
                                             int N, int K) {
    const int tid = threadIdx.x;
    const int bn = blockIdx.x * 128, bm = blockIdx.y * 128;
    const int w = tid >> 6, l = tid & 63;
    const int wr = w >> 1, wc = w & 1;
    const int g = l >> 4, ln16 = l & 15;

    __shared__ u16 A_lds[4096];     // [koff][row][8]
    __shared__ u16 B_lds[4096];

    f32x4 acc[4][4];
#pragma unroll
    for (int m = 0; m < 4; ++m)
#pragma unroll
        for (int n = 0; n < 4; ++n) acc[m][n] = {0.f, 0.f, 0.f, 0.f};

    const int c0 = tid, c1 = tid + 256;
    const int r0 = c0 & 127, k0off = (c0 >> 7) * 8;
    const int r1 = c1 & 127, k1off = (c1 >> 7) * 8;

    for (int k0 = 0; k0 < K; k0 += 32) {
        __syncthreads();
        gload16(A  + (size_t)(bm + r0) * K + k0 + k0off, &A_lds[c0 * 8]);
        gload16(A  + (size_t)(bm + r1) * K + k0 + k1off, &A_lds[c1 * 8]);
        gload16(Bm + (size_t)(bn + r0) * K + k0 + k0off, &B_lds[c0 * 8]);
        gload16(Bm + (size_t)(bn + r1) * K + k0 + k1off, &B_lds[c1 * 8]);
        __syncthreads();

        short8 af[4], bf[4];
#pragma unroll
        for (int m = 0; m < 4; ++m)
            af[m] = *reinterpret_cast<const short8*>(&A_lds[g * 1024 + (wr*64 + m*16 + ln16) * 8]);
#pragma unroll
        for (int n = 0; n < 4; ++n)
            bf[n] = *reinterpret_cast<const short8*>(&B_lds[g * 1024 + (wc*64 + n*16 + ln16) * 8]);
#pragma unroll
        for (int m = 0; m < 4; ++m)
#pragma unroll
            for (int n = 0; n < 4; ++n)
                acc[m][n] = mfma16(af[m], bf[n], acc[m][n]);
    }

#pragma unroll
    for (int m = 0; m < 4; ++m)
#pragma unroll
        for (int n = 0; n < 4; ++n)
#pragma unroll
            for (int r = 0; r < 4; ++r)
                store1<TC>(&C[(size_t)(bm + wr*64 + m*16 + g*4 + r) * N + bn + wc*64 + n*16 + ln16],
                           acc[m][n][r]);
}

// ---------------------------------------------------------------------------
// LayerNorm over L=512 per row, f32.
// ---------------------------------------------------------------------------
__global__ __launch_bounds__(256) void ln_kernel(const float* __restrict__ pre,
                                                 const float* __restrict__ w,
                                                 const float* __restrict__ bias,
                                                 float* __restrict__ out) {
    const int row = blockIdx.x;
    const int tid = threadIdx.x;
    __shared__ float red[256];
    const size_t base = (size_t)row * L_;
    float x0 = pre[base + tid];
    float x1 = pre[base + tid + 256];
    red[tid] = x0 + x1;
    __syncthreads();
    for (int o = 128; o; o >>= 1) { if (tid < o) red[tid] += red[tid + o]; __syncthreads(); }
    float mu = red[0] * (1.0f / L_);
    __syncthreads();
    float d0 = x0 - mu, d1 = x1 - mu;
    red[tid] = d0 * d0 + d1 * d1;
    __syncthreads();
    for (int o = 128; o; o >>= 1) { if (tid < o) red[tid] += red[tid + o]; __syncthreads(); }
    float rstd = rsqrtf(red[0] * (1.0f / L_) + 1e-5f);
    out[base + tid]       = d0 * rstd * w[tid]       + bias[tid];
    out[base + tid + 256] = d1 * rstd * w[tid + 256] + bias[tid + 256];
}

// ---------------------------------------------------------------------------
// f32 -> bf16 convert (4 elems/thread)
// ---------------------------------------------------------------------------
__global__ __launch_bounds__(256) void cvt_bf16(const float* __restrict__ in,
                                                u16* __restrict__ out) {
    size_t i = ((size_t)blockIdx.x * 256 + threadIdx.x) * 4;
    f32x4 v = *reinterpret_cast<const f32x4*>(&in[i]);
    u16x4 o; o[0]=f2bf(v[0]); o[1]=f2bf(v[1]); o[2]=f2bf(v[2]); o[3]=f2bf(v[3]);
    *reinterpret_cast<u16x4*>(&out[i]) = o;
}

// ---------------------------------------------------------------------------
// absorb: q'[hh][s][l] = sum_d qb[s][h0col + hh*128 + d] * Wuk[hh*128+d][l]
// ---------------------------------------------------------------------------
__global__ __launch_bounds__(256) void absorb(const u16* __restrict__ qb,
                                              const float* __restrict__ Wuk,
                                              u16* __restrict__ qp,
                                              int h0col) {
    const int st = blockIdx.x, lt = blockIdx.y, hh = blockIdx.z;
    const int tid = threadIdx.x;
    const int w = tid >> 6, l = tid & 63;
    const int g = l >> 4, ln16 = l & 15;

    __shared__ char A_lds[16384];
    __shared__ char B_lds[16384];

#pragma unroll
    for (int i = 0; i < 4; ++i) {
        int idx = tid + i * 256;
        int row = idx >> 4, c8 = idx & 15;
        int byte = (row * 256 + c8 * 16) ^ ((row & 7) << 4);
        *reinterpret_cast<u16x8*>(A_lds + byte) =
            *reinterpret_cast<const u16x8*>(qb + (size_t)(st*64 + row) * D_ + h0col + hh*128 + c8*8);
    }
#pragma unroll
    for (int i = 0; i < 32; ++i) {
        int idx = tid + i * 256;
        int k = idx >> 6, n = idx & 63;
        int byte = (n * 256 + k * 2) ^ ((n & 7) << 4);
        *reinterpret_cast<u16*>(B_lds + byte) =
            f2bf(Wuk[(size_t)(hh*128 + k) * L_ + lt*64 + n]);
    }
    __syncthreads();

    f32x4 acc[4];
#pragma unroll
    for (int a = 0; a < 4; ++a) acc[a] = {0,0,0,0};

#pragma unroll
    for (int kc = 0; kc < 4; ++kc) {
        const int arow = w*16 + ln16;
        short8 af = *reinterpret_cast<const short8*>(
            A_lds + ((arow*256 + kc*64 + g*16) ^ ((arow & 7) << 4)));
#pragma unroll
        for (int a = 0; a < 4; ++a) {
            const int brow = a*16 + ln16;
            short8 bf = *reinterpret_cast<const short8*>(
                B_lds + ((brow*256 + kc*64 + g*16) ^ ((brow & 7) << 4)));
            acc[a] = mfma16(af, bf, acc[a]);
        }
    }
#pragma unroll
    for (int a = 0; a < 4; ++a)
#pragma unroll
        for (int r = 0; r < 4; ++r)
            qp[((size_t)hh * S_ + st*64 + w*16 + g*4 + r) * L_ + lt*64 + a*16 + ln16] =
                f2bf(acc[a][r]);
}

// ---------------------------------------------------------------------------
// flash_split: grid (16 qt2, 8 hh, 4 kv-chunk), block 256 (4 waves x 32 q).
// Each wave owns 32 q-rows (2 fragments) -> every K-fragment LDS read feeds
// 2 MFMAs, halving K LDS traffic vs the 8-wave/16-q version.
// LDS 64 KB (K 32 + V 16 + P 16) -> 2 blocks/CU.
// Writes normalized partial ctx (bf16) + LSE (f32); empty chunk -> LSE=-3e38.
// ---------------------------------------------------------------------------
__global__ __launch_bounds__(256) void flash_split(const u16* __restrict__ qp,
                                                   const u16* __restrict__ kbf,
                                                   const u16* __restrict__ vbf,
                                                   u16* __restrict__ opart,
                                                   float* __restrict__ ml,
                                                   int h0) {
    const int qt2 = 15 - blockIdx.x;     // heavy tiles first
    const int hh = blockIdx.y;
    const int c  = blockIdx.z;
    const int h  = h0 + hh;
    const int tid = threadIdx.x;
    const int w = tid >> 6, l = tid & 63;
    const int g = l >> 4, ln16 = l & 15;

    const int kt0 = c * 8;
    const int kt1 = min(2*qt2 + 1, kt0 + 7);
    if (kt1 < kt0) {                      // empty chunk: mark LSE absent
        if (tid < 128) ml[(size_t)(c*8 + hh)*S_ + qt2*128 + tid] = -3e38f;
        return;
    }

    __shared__ u16 K_lds[16384];          // 32 KB: [kslice 0..31][row 0..63][8]
    __shared__ char V_lds[16384];         // [dv 0..127][kv 0..63] u16, ^swz
    __shared__ char P_lds[16384];         // 4 waves x 2 qf x 2 KB
    char* P_my0 = P_lds + w * 4096;
    char* P_my1 = P_lds + w * 4096 + 2048;

    // Q' registers: 2 fragments of 16 q-rows each; wave owns rows w*32..w*32+31
    short8 qreg0[16], qreg1[16];
    {
        const u16* qb0 = qp + ((size_t)hh * S_ + qt2*128 + w*32 + ln16) * L_ + g*8;
        const u16* qb1 = qb0 + (size_t)16 * L_;
#pragma unroll
        for (int kc = 0; kc < 16; ++kc) {
            qreg0[kc] = *reinterpret_cast<const short8*>(qb0 + kc*32);
            qreg1[kc] = *reinterpret_cast<const short8*>(qb1 + kc*32);
        }
    }

    float m_run0 = -3e38f, l_run0 = 0.f;
    float m_run1 = -3e38f, l_run1 = 0.f;
    f32x4 acc0[8], acc1[8];
#pragma unroll
    for (int cb = 0; cb < 8; ++cb) { acc0[cb] = {0,0,0,0}; acc1[cb] = {0,0,0,0}; }

    const int sq0 = qt2*128 + w*32 + ln16;        // lane's q row, fragment 0
    const int sq1 = sq0 + 16;                      // fragment 1
    const float scale = 0.08838834764831845f;

    for (int kt = kt0; kt <= kt1; ++kt) {
        __syncthreads();
        // ---- stage V transposed (lanes sweep kv -> contiguous-row stores)
        {
            const u16* vsrc = vbf + (size_t)kt * 64 * D_ + h * DH_;
            const int kv = tid & 63;
#pragma unroll
            for (int p = 0; p < 4; ++p) {
                int dg = (tid >> 6) + p * 4;
                u16x8 v8 = *reinterpret_cast<const u16x8*>(vsrc + (size_t)kv * D_ + dg*8);
#pragma unroll
                for (int j = 0; j < 8; ++j) {
                    int dv = dg*8 + j;
                    *reinterpret_cast<u16*>(V_lds + ((dv*128 + kv*2) ^ (j << 4))) = v8[j];
                }
            }
        }
        // ---- stage K half 0 (cols 0..255) via DMA
        const u16* ksrc = kbf + (size_t)kt * 64 * L_;
#pragma unroll
        for (int i = 0; i < 8; ++i) {
            int ch = tid + i * 256;
            int s = ch >> 6, row = ch & 63;
            gload16(ksrc + (size_t)row * L_ + s*8, &K_lds[ch * 8]);
        }
        __syncthreads();

        f32x4 sacc0[4], sacc1[4];
#pragma unroll
        for (int a = 0; a < 4; ++a) { sacc0[a] = {0,0,0,0}; sacc1[a] = {0,0,0,0}; }
#pragma unroll
        for (int a = 0; a < 4; ++a) {
            const int row = a*16 + ln16;
#pragma unroll
            for (int kc = 0; kc < 8; ++kc) {
                short8 kf = *reinterpret_cast<const short8*>(&K_lds[((kc*4 + g)*64 + row) * 8]);
                sacc0[a] = mfma16(kf, qreg0[kc], sacc0[a]);
                sacc1[a] = mfma16(kf, qreg1[kc], sacc1[a]);
            }
        }
        __syncthreads();
        // ---- stage K half 1 (cols 256..511)
#pragma unroll
        for (int i = 0; i < 8; ++i) {
            int ch = tid + i * 256;
            int s = ch >> 6, row = ch & 63;
            gload16(ksrc + (size_t)row * L_ + 256 + s*8, &K_lds[ch * 8]);
        }
        __syncthreads();
#pragma unroll
        for (int a = 0; a < 4; ++a) {
            const int row = a*16 + ln16;
#pragma unroll
            for (int kc = 0; kc < 8; ++kc) {
                short8 kf = *reinterpret_cast<const short8*>(&K_lds[((kc*4 + g)*64 + row) * 8]);
                sacc0[a] = mfma16(kf, qreg0[8 + kc], sacc0[a]);
                sacc1[a] = mfma16(kf, qreg1[8 + kc], sacc1[a]);
            }
        }

        // ---- online softmax, fragment 0 (lane owns q = sq0)
        float fac0, fac1;
        {
            float p[4][4];
            float tmax = -3e38f;
#pragma unroll
            for (int a = 0; a < 4; ++a)
#pragma unroll
                for (int r = 0; r < 4; ++r) {
                    int t = kt*64 + a*16 + g*4 + r;
                    float v = (t <= sq0) ? sacc0[a][r] * scale : -3e38f;
                    p[a][r] = v;
                    tmax = fmaxf(tmax, v);
                }
            tmax = fmaxf(tmax, __shfl_xor(tmax, 16, 64));
            tmax = fmaxf(tmax, __shfl_xor(tmax, 32, 64));
            float m_new = fmaxf(m_run0, tmax);
            fac0 = __expf(m_run0 - m_new);
            float rsum = 0.f;
#pragma unroll
            for (int a = 0; a < 4; ++a)
#pragma unroll
                for (int r = 0; r < 4; ++r) {
                    float e = __expf(p[a][r] - m_new);
                    p[a][r] = e;
                    rsum += e;
                }
            rsum += __shfl_xor(rsum, 16, 64);
            rsum += __shfl_xor(rsum, 32, 64);
            l_run0 = l_run0 * fac0 + rsum;
            m_run0 = m_new;
            const int ps = (ln16 & 7) << 4;
#pragma unroll
            for (int a = 0; a < 4; ++a) {
                u16x4 quad;
#pragma unroll
                for (int r = 0; r < 4; ++r) quad[r] = f2bf(p[a][r]);
                *reinterpret_cast<u16x4*>(P_my0 + ((ln16*128 + a*32 + g*8) ^ ps)) = quad;
            }
        }
        // ---- online softmax, fragment 1 (lane owns q = sq1)
        {
            float p[4][4];
            float tmax = -3e38f;
#pragma unroll
            for (int a = 0; a < 4; ++a)
#pragma unroll
                for (int r = 0; r < 4; ++r) {
                    int t = kt*64 + a*16 + g*4 + r;
                    float v = (t <= sq1) ? sacc1[a][r] * scale : -3e38f;
                    p[a][r] = v;
                    tmax = fmaxf(tmax, v);
                }
            tmax = fmaxf(tmax, __shfl_xor(tmax, 16, 64));
            tmax = fmaxf(tmax, __shfl_xor(tmax, 32, 64));
            float m_new = fmaxf(m_run1, tmax);
            fac1 = __expf(m_run1 - m_new);
            float rsum = 0.f;
#pragma unroll
            for (int a = 0; a < 4; ++a)
#pragma unroll
                for (int r = 0; r < 4; ++r) {
                    float e = __expf(p[a][r] - m_new);
                    p[a][r] = e;
                    rsum += e;
                }
            rsum += __shfl_xor(rsum, 16, 64);
            rsum += __shfl_xor(rsum, 32, 64);
            l_run1 = l_run1 * fac1 + rsum;
            m_run1 = m_new;
            const int ps = (ln16 & 7) << 4;
#pragma unroll
            for (int a = 0; a < 4; ++a) {
                u16x4 quad;
#pragma unroll
                for (int r = 0; r < 4; ++r) quad[r] = f2bf(p[a][r]);
                *reinterpret_cast<u16x4*>(P_my1 + ((ln16*128 + a*32 + g*8) ^ ps)) = quad;
            }
        }

        // ---- rescale ctx accumulators
        float fr0[4], fr1[4];
#pragma unroll
        for (int r = 0; r < 4; ++r) {
            fr0[r] = __shfl(fac0, g*4 + r, 64);
            fr1[r] = __shfl(fac1, g*4 + r, 64);
        }
#pragma unroll
        for (int cb = 0; cb < 8; ++cb)
#pragma unroll
            for (int r = 0; r < 4; ++r) {
                acc0[cb][r] *= fr0[r];
                acc1[cb][r] *= fr1[r];
            }

        // ---- PV (vf shared across the two q-fragments)
#pragma unroll
        for (int kc2 = 0; kc2 < 2; ++kc2) {
            const int psw = (ln16 & 7) << 4;
            short8 pf0 = *reinterpret_cast<const short8*>(
                P_my0 + ((ln16*128 + kc2*64 + g*16) ^ psw));
            short8 pf1 = *reinterpret_cast<const short8*>(
                P_my1 + ((ln16*128 + kc2*64 + g*16) ^ psw));
#pragma unroll
            for (int cb = 0; cb < 8; ++cb) {
                const int dv = cb*16 + ln16;
                short8 vf = *reinterpret_cast<const short8*>(
                    V_lds + ((dv*128 + kc2*64 + g*16) ^ ((dv & 7) << 4)));
                acc0[cb] = mfma16(pf0, vf, acc0[cb]);
                acc1[cb] = mfma16(pf1, vf, acc1[cb]);
            }
        }
    }

    // ---- epilogue: normalized partials + LSE (two fragments)
    {
        float inv = 1.0f / l_run0;
        float lse = m_run0 + __logf(l_run0);
        float ir[4];
#pragma unroll
        for (int r = 0; r < 4; ++r) ir[r] = __shfl(inv, g*4 + r, 64);
#pragma unroll
        for (int cb = 0; cb < 8; ++cb)
#pragma unroll
            for (int r = 0; r < 4; ++r) {
                int q = qt2*128 + w*32 + g*4 + r;
                opart[((size_t)(c*8 + hh)*S_ + q)*128 + cb*16 + ln16] = f2bf(acc0[cb][r] * ir[r]);
            }
        if (g == 0) ml[(size_t)(c*8 + hh)*S_ + qt2*128 + w*32 + ln16] = lse;
    }
    {
        float inv = 1.0f / l_run1;
        float lse = m_run1 + __logf(l_run1);
        float ir[4];
#pragma unroll
        for (int r = 0; r < 4; ++r) ir[r] = __shfl(inv, g*4 + r, 64);
#pragma unroll
        for (int cb = 0; cb < 8; ++cb)
#pragma unroll
            for (int r = 0; r < 4; ++r) {
                int q = qt2*128 + w*32 + 16 + g*4 + r;
                opart[((size_t)(c*8 + hh)*S_ + q)*128 + cb*16 + ln16] = f2bf(acc1[cb][r] * ir[r]);
            }
        if (g == 0) ml[(size_t)(c*8 + hh)*S_ + qt2*128 + w*32 + 16 + ln16] = lse;
    }
}

// ---------------------------------------------------------------------------
// combine: ctx = LSE-weighted blend of the 4 kv-chunk partials.
// ---------------------------------------------------------------------------
__global__ __launch_bounds__(256) void combine(const u16* __restrict__ opart,
                                               const float* __restrict__ ml,
                                               u16* __restrict__ ctx,
                                               int h0) {
    int t = blockIdx.x * 256 + threadIdx.x;
    int qh = t >> 4;
    int q = qh >> 3, hh = qh & 7;
    int dv0 = (t & 15) * 8;

    float ls[4], m = -3e38f;
#pragma unroll
    for (int c = 0; c < 4; ++c) {
        ls[c] = ml[(size_t)(c*8 + hh) * S_ + q];
        m = fmaxf(m, ls[c]);
    }
    float e[4], s = 0.f;
#pragma unroll
    for (int c = 0; c < 4; ++c) { e[c] = __expf(ls[c] - m); s += e[c]; }
    float is = 1.0f / s;

    float accv[8] = {};
#pragma unroll
    for (int c = 0; c < 4; ++c) {
        if (e[c] > 0.f) {
            u16x8 a = *reinterpret_cast<const u16x8*>(
                &opart[((size_t)(c*8 + hh)*S_ + q)*128 + dv0]);
#pragma unroll
            for (int j = 0; j < 8; ++j) accv[j] += e[c] * bf2f(a[j]);
        }
    }
    u16x8 o;
#pragma unroll
    for (int j = 0; j < 8; ++j) o[j] = f2bf(accv[j] * is);
    *reinterpret_cast<u16x8*>(&ctx[(size_t)q * D_ + (h0 + hh) * DH_ + dv0]) = o;
}

// ---------------------------------------------------------------------------
// ws (44.25 MB of proven 48):
//   [ 0,16) xb_bf[0,8)+wslot[8,16) -> reused as qprime [0,16)
//   [16,24) qb_bf  [24,32) vb_bf  [32,36) ckv_bf (full M)  [36,44) ctx_bf
//   [44,44.25) ml
// d_out reuse: ckvp f32 in out_b1 region; opart (16 MB bf16) in out_b region.
// ---------------------------------------------------------------------------
extern "C" void kernel_launch(void* const* d_in, const int* in_sizes, int n_in,
                              void* d_out, int out_size, void* d_ws, size_t ws_size,
                              hipStream_t stream) {
    const float* x    = (const float*)d_in[0];
    const float* Wq   = (const float*)d_in[1];
    const float* Wdkv = (const float*)d_in[2];
    const float* Wuk  = (const float*)d_in[3];
    const float* Wuv  = (const float*)d_in[4];
    const float* Wo   = (const float*)d_in[5];
    const float* lnw  = (const float*)d_in[6];
    const float* lnb  = (const float*)d_in[7];

    float* out = (float*)d_out;
    float* ckv = out + (size_t)M_ * D_;
    float* ckvp = out + (size_t)S_ * D_;              // out_b1 region scratch

    char* ws = (char*)d_ws;
    u16* xb_bf  = (u16*)(ws);
    u16* wslot  = (u16*)(ws + (size_t)8388608);
    u16* qprime = (u16*)(ws);                          // overlaps xb+wslot
    u16* qb_bf  = (u16*)(ws + (size_t)16777216);
    u16* vb_bf  = (u16*)(ws + (size_t)25165824);
    u16* ckv_bf = (u16*)(ws + (size_t)33554432);
    u16* ctx_bf = (u16*)(ws + (size_t)37748736);
    float* ml   = (float*)(ws + (size_t)46137344);     // 256 KB

    dim3 blk(256);

    for (int b = 0; b < B_; ++b) {
        const float* xb     = x + (size_t)b * S_ * D_;
        float*       ckv_b  = ckv + (size_t)b * S_ * L_;
        u16*         ckvbf_b= ckv_bf + (size_t)b * S_ * L_;
        float*       outb   = out + (size_t)b * S_ * D_;
        u16*         opart  = (u16*)outb;                          // 16 MB

        cvt_bf16<<<dim3(4096), blk, 0, stream>>>(xb, xb_bf);

        cvt_bf16<<<dim3(1024), blk, 0, stream>>>(Wdkv, wslot);
        mgemm<float><<<dim3(L_/128, S_/128), blk, 0, stream>>>(xb_bf, wslot, ckvp, L_, D_);
        ln_kernel<<<dim3(S_), blk, 0, stream>>>(ckvp, lnw, lnb, ckv_b);
        cvt_bf16<<<dim3(1024), blk, 0, stream>>>(ckv_b, ckvbf_b);

        cvt_bf16<<<dim3(4096), blk, 0, stream>>>(Wq, wslot);
        mgemm<u16><<<dim3(D_/128, S_/128), blk, 0, stream>>>(xb_bf, wslot, qb_bf, D_, D_);

        cvt_bf16<<<dim3(1024), blk, 0, stream>>>(Wuv, wslot);
        mgemm<u16><<<dim3(D_/128, S_/128), blk, 0, stream>>>(ckvbf_b, wslot, vb_bf, D_, L_);

        for (int hc = 0; hc < 2; ++hc) {
            absorb<<<dim3(S_/64, L_/64, 8), blk, 0, stream>>>(
                qb_bf, Wuk + (size_t)hc * 8 * DH_ * L_, qprime, hc * 8 * DH_);
            flash_split<<<dim3(16, 8, 4), blk, 0, stream>>>(
                qprime, ckvbf_b, vb_bf, opart, ml, hc * 8);
            combine<<<dim3(1024), blk, 0, stream>>>(opart, ml, ctx_bf, hc * 8);
        }

        cvt_bf16<<<dim3(4096), blk, 0, stream>>>(Wo, wslot);
        mgemm<float><<<dim3(D_/128, S_/128), blk, 0, stream>>>(ctx_bf, wslot, outb, D_, D_);
    }
}